// Round 7
// baseline (163.689 us; speedup 1.0000x reference)
//
#include <hip/hip_runtime.h>
#include <hip/hip_bf16.h>

typedef __bf16 bf16;
typedef __bf16 bf16x4 __attribute__((ext_vector_type(4)));
typedef __bf16 bf16x8 __attribute__((ext_vector_type(8)));
typedef float f32x4 __attribute__((ext_vector_type(4)));

#define DIM 768
#define HW 1024          // 32*32
#define BATCH 16
#define M_TOTAL (BATCH * HW)   // 16384
#define NKT 24                 // K-steps of 32

#define AS1 __attribute__((address_space(1)))
#define AS3 __attribute__((address_space(3)))

// ======================== k-permutation convention =========================
// All bf16 [.][768] activation buffers and Wb[768][768] store the k (channel)
// dimension permuted within each 32-group: physical position p = 8g+j holds
// logical k = 4g+j (j<4) or 16+4g+(j-4) (j>=4). mfma_f32_16x16x32_bf16
// fragments are then 16B-contiguous -> single ds_read_b128 per fragment.
// k2pos(kk) = (((kk&15)>>2)<<3) + (kk&3) + ((kk>>4)<<2).  (validated R4-R6)

// ---------------- weight convert: f32 -> bf16, k-permuted ----------------
__global__ void wcvt3_kernel(const float4* __restrict__ w1, const float4* __restrict__ w2,
                             const float4* __restrict__ w3,
                             bf16x8* __restrict__ o1, bf16x8* __restrict__ o2,
                             bf16x8* __restrict__ o3) {
    const int b = blockIdx.x;              // 0..863
    const int which = b / 288;
    const int i = (b % 288) * 256 + threadIdx.x;   // output 16B blocks
    const float4* w = which == 0 ? w1 : which == 1 ? w2 : w3;
    bf16x8* o = which == 0 ? o1 : which == 1 ? o2 : o3;
    const int row = i / 96, br = i % 96;
    const int q = br >> 2, g = br & 3;
    float4 lo = w[row * 192 + q * 8 + g];
    float4 hi = w[row * 192 + q * 8 + g + 4];
    bf16x8 r = { (bf16)lo.x, (bf16)lo.y, (bf16)lo.z, (bf16)lo.w,
                 (bf16)hi.x, (bf16)hi.y, (bf16)hi.z, (bf16)hi.w };
    o[row * 96 + br] = r;
}

// ------- transpose + convert: x[16][768][1024] f32 -> xb[16384][768p] bf16 -------
__global__ void transpose_cvt_kernel(const float* __restrict__ x, bf16* __restrict__ xb) {
    __shared__ float tile[32][33];
    const int b = blockIdx.z;
    const int hw0 = blockIdx.x * 32;
    const int c0 = blockIdx.y * 32;
    const int tx = threadIdx.x, ty = threadIdx.y;  // 32 x 8

    const float* src = x + ((size_t)b * DIM + c0) * HW + hw0;
#pragma unroll
    for (int j = 0; j < 4; j++)
        tile[ty + 8 * j][tx] = src[(size_t)(ty + 8 * j) * HW + tx];
    __syncthreads();
    const int ptx = (((tx & 15) >> 2) << 3) + (tx & 3) + ((tx >> 4) << 2);  // k2pos
    bf16* dst = xb + ((size_t)b * HW + hw0) * DIM + c0;
#pragma unroll
    for (int j = 0; j < 4; j++)
        dst[(size_t)(ty + 8 * j) * DIM + ptx] = (bf16)tile[tx][ty + 8 * j];
}

// ---------------- GEMM: C[M][768] = A[M][768] * W^T (+bias) ----------------
// 128x128 tile, BK=32, 4 waves (2x2), grid 768 = 3 blocks/CU (12 waves/CU).
// 3 LDS buffers, staged 2 K-steps ahead, ONE raw s_barrier per step, counted
// vmcnt(4) (issue-to-wait distance = one full K-step). k-permuted layout ->
// 1 ds_read_b128 per fragment. 16B-block swizzle s(R)=(R^(R>>2))&3: linear
// LDS dest + pre-swizzled global source + same XOR on frag reads (2-way, free).
// MODE 0: write bf16 [n][768] k-permuted (+bias). MODE 1: f32 NCHW (+bias).
template <int MODE>
__global__ __launch_bounds__(256, 3) void gemm_kernel(
    const bf16* __restrict__ A,    // [M][768] k-permuted
    const bf16* __restrict__ Bw,   // [768][768] rows linear, cols k-permuted
    const float* __restrict__ bias,
    void* __restrict__ out)
{
    constexpr int K = DIM;
    __shared__ bf16 As[3][128][32];   // 8 KiB each
    __shared__ bf16 Bs[3][128][32];

    const int t = threadIdx.x;
    const int lane = t & 63;
    const int wave = t >> 6;
    const int wr = wave >> 1, wc = wave & 1;

    // grid 768 = 8 XCD chunks of 96 = 16 m-tiles x 6 n-tiles (n fastest:
    // consecutive blocks in a chunk share the A-panel).
    const int bid = blockIdx.x;
    const int virt = (bid & 7) * 96 + (bid >> 3);
    const int mI = virt / 6;
    const int m0 = mI * 128;
    const int n0 = (virt - mI * 6) * 128;

    const int fr = lane & 15;
    const int fq = lane >> 4;

    f32x4 acc[4][4] = {};

    const int sr = t >> 2;     // staging row (0..63, +64 for j=1)
    const int sb = t & 3;      // staging 16B block in 64B row

    auto stage = [&](int kt, int buf) {       // 4 global_load_lds / thread
        const int k0 = kt * 32;
#pragma unroll
        for (int j = 0; j < 2; j++) {
            const int r = sr + j * 64;
            const int gs = sb ^ ((r ^ (r >> 2)) & 3);
            __builtin_amdgcn_global_load_lds(
                (const AS1 void*)(A + (size_t)(m0 + r) * K + k0 + gs * 8),
                (AS3 void*)&As[buf][r][sb * 8], 16, 0, 0);
            __builtin_amdgcn_global_load_lds(
                (const AS1 void*)(Bw + (size_t)(n0 + r) * K + k0 + gs * 8),
                (AS3 void*)&Bs[buf][r][sb * 8], 16, 0, 0);
        }
    };

    // prologue: tiles 0,1 in flight; wait tile 0
    stage(0, 0);
    stage(1, 1);
    asm volatile("s_waitcnt vmcnt(4)" ::: "memory");
    __builtin_amdgcn_s_barrier();
    __builtin_amdgcn_sched_barrier(0);

    int c0 = 0, c1 = 1, c2 = 2;
    for (int kt = 0; kt < NKT; ++kt) {
        if (kt + 2 < NKT) stage(kt + 2, c2);

        bf16x8 aF[4], bF[4];
#pragma unroll
        for (int mi = 0; mi < 4; mi++) {
            const int R = wr * 64 + mi * 16 + fr;
            aF[mi] = *(const bf16x8*)(&As[c0][R][0] + ((fq ^ ((R ^ (R >> 2)) & 3)) << 3));
        }
#pragma unroll
        for (int ni = 0; ni < 4; ni++) {
            const int R = wc * 64 + ni * 16 + fr;
            bF[ni] = *(const bf16x8*)(&Bs[c0][R][0] + ((fq ^ ((R ^ (R >> 2)) & 3)) << 3));
        }
        __builtin_amdgcn_s_setprio(1);
#pragma unroll
        for (int mi = 0; mi < 4; mi++)
#pragma unroll
            for (int ni = 0; ni < 4; ni++)
                acc[mi][ni] = __builtin_amdgcn_mfma_f32_16x16x32_bf16(aF[mi], bF[ni], acc[mi][ni], 0, 0, 0);
        __builtin_amdgcn_s_setprio(0);

        if (kt < NKT - 1) {
            if (kt + 2 < NKT) { asm volatile("s_waitcnt vmcnt(4)" ::: "memory"); }
            else              { asm volatile("s_waitcnt vmcnt(0)" ::: "memory"); }
            __builtin_amdgcn_s_barrier();
            __builtin_amdgcn_sched_barrier(0);   // fence: no next-iter ds_read hoists above barrier
        }
        const int tmp = c0; c0 = c1; c1 = c2; c2 = tmp;
    }

    // ---------------- epilogue ----------------
    if (MODE == 0) {
        bf16* o = (bf16*)out;
#pragma unroll
        for (int mi = 0; mi < 4; mi++) {
            const int row = m0 + wr * 64 + mi * 16 + fq * 4;
#pragma unroll
            for (int ni = 0; ni < 4; ni++) {
                const int col = n0 + wc * 64 + ni * 16 + fr;   // logical channel
                const int pcol = n0 + wc * 64 + ((ni >> 1) << 5) + ((fr >> 2) << 3)
                               + (fr & 3) + ((ni & 1) << 2);   // k2pos
                const float bv = bias[col];
#pragma unroll
                for (int r = 0; r < 4; r++)
                    o[(size_t)(row + r) * DIM + pcol] = (bf16)(acc[mi][ni][r] + bv);
            }
        }
    } else {
        float* o = (float*)out;
#pragma unroll
        for (int mi = 0; mi < 4; mi++) {
            const int nb = m0 + wr * 64 + mi * 16 + (lane >> 4) * 4;
            const int bI = nb >> 10, hw = nb & 1023;
#pragma unroll
            for (int ni = 0; ni < 4; ni++) {
                const int col = n0 + wc * 64 + ni * 16 + fr;
                f32x4 v = acc[mi][ni] + bias[col];
                *(f32x4*)(o + ((size_t)bI * DIM + col) * HW + hw) = v;
            }
        }
    }
}

// ---------------- LayerNorm + exact GELU, in-place on k-permuted bf16 rows ----------------
__global__ __launch_bounds__(256) void ln_gelu_kernel(
    bf16* __restrict__ h, const float* __restrict__ g, const float* __restrict__ beta)
{
    const int wave = threadIdx.x >> 6;
    const int lane = threadIdx.x & 63;
    const int n = blockIdx.x * 4 + wave;
    bf16* row = h + (size_t)n * DIM;

    float v[12];
    float s = 0.f, ss = 0.f;
#pragma unroll
    for (int j = 0; j < 3; j++) {
        bf16x4 x = *(const bf16x4*)(row + j * 256 + lane * 4);
#pragma unroll
        for (int i = 0; i < 4; i++) {
            float f = (float)x[i];
            v[j * 4 + i] = f;
            s += f;
            ss += f * f;
        }
    }
#pragma unroll
    for (int off = 32; off > 0; off >>= 1) {
        s += __shfl_xor(s, off);
        ss += __shfl_xor(ss, off);
    }
    const float mu = s * (1.f / DIM);
    const float var = ss * (1.f / DIM) - mu * mu;
    const float rstd = rsqrtf(var + 1e-6f);

#pragma unroll
    for (int j = 0; j < 3; j++) {
        bf16x4 r;
#pragma unroll
        for (int i = 0; i < 4; i++) {
            const int c = j * 256 + lane * 4 + i;   // physical position
            const int p = (lane * 4 + i) & 31;
            const int kk = ((p >> 3) << 2) + (p & 7) + ((p & 4) ? 12 : 0);  // pos2k
            const int gi = (c & ~31) + kk;          // logical channel for gamma/beta
            float y = (v[j * 4 + i] - mu) * rstd * g[gi] + beta[gi];
            y = 0.5f * y * (1.f + erff(y * 0.70710678118f));
            r[i] = (bf16)y;
        }
        *(bf16x4*)(row + j * 256 + lane * 4) = r;
    }
}

extern "C" void kernel_launch(void* const* d_in, const int* in_sizes, int n_in,
                              void* d_out, int out_size, void* d_ws, size_t ws_size,
                              hipStream_t stream) {
    const float* x   = (const float*)d_in[0];
    const float* W1  = (const float*)d_in[1];
    const float* b1  = (const float*)d_in[2];
    const float* g1  = (const float*)d_in[3];
    const float* be1 = (const float*)d_in[4];
    const float* W2  = (const float*)d_in[5];
    const float* b2  = (const float*)d_in[6];
    const float* g2  = (const float*)d_in[7];
    const float* be2 = (const float*)d_in[8];
    const float* W3  = (const float*)d_in[9];
    const float* b3  = (const float*)d_in[10];
    float* out = (float*)d_out;

    bf16* Wb1  = (bf16*)d_ws;
    bf16* Wb2  = Wb1 + (size_t)DIM * DIM;
    bf16* Wb3  = Wb2 + (size_t)DIM * DIM;
    bf16* buf0 = Wb3 + (size_t)DIM * DIM;          // 16384*768 bf16
    bf16* buf1 = buf0 + (size_t)M_TOTAL * DIM;

    // weights -> bf16 k-permuted
    wcvt3_kernel<<<864, 256, 0, stream>>>((const float4*)W1, (const float4*)W2, (const float4*)W3,
                                          (bf16x8*)Wb1, (bf16x8*)Wb2, (bf16x8*)Wb3);

    // x NCHW -> [n][c] bf16 k-permuted
    transpose_cvt_kernel<<<dim3(32, 24, 16), dim3(32, 8), 0, stream>>>(x, buf0);

    const int ggrid = (M_TOTAL / 128) * (DIM / 128);   // 128*6 = 768 = 3/CU
    // layer 1
    gemm_kernel<0><<<ggrid, 256, 0, stream>>>(buf0, Wb1, b1, buf1);
    ln_gelu_kernel<<<M_TOTAL / 4, 256, 0, stream>>>(buf1, g1, be1);
    // layer 2
    gemm_kernel<0><<<ggrid, 256, 0, stream>>>(buf1, Wb2, b2, buf0);
    ln_gelu_kernel<<<M_TOTAL / 4, 256, 0, stream>>>(buf0, g2, be2);
    // layer 3 -> NCHW f32 output
    gemm_kernel<1><<<ggrid, 256, 0, stream>>>(buf0, Wb3, b3, out);
}